// Round 5
// baseline (467.512 us; speedup 1.0000x reference)
//
#include <hip/hip_runtime.h>
#include <cstddef>

#define BB 4
#define CC 256
#define NN 4096
#define NI 32

typedef __attribute__((ext_vector_type(8))) short bf16x8;   // 8 bf16 = 4 VGPRs
typedef __attribute__((ext_vector_type(16))) float f32x16;  // MFMA 32x32 acc
typedef unsigned short ushort_t;
typedef unsigned int uint32;

typedef union { uint32 u[4]; bf16x8 v; } fragU;

__device__ __forceinline__ uint32 f2bf_bits(float f) {
    union { float f; uint32 u; } v; v.f = f;
    return (v.u + 0x7fffu + ((v.u >> 16) & 1u)) >> 16;   // RNE
}
__device__ __forceinline__ uint32 pack2bf(float a, float b) {
    return f2bf_bits(a) | (f2bf_bits(b) << 16);
}

// ---------------------------------------------------------------- q,k projections
// Outputs token-major bf16: qT/kT [B][N][NI] — exactly MFMA frag order.
__global__ __launch_bounds__(256) void qk_kernel(
    const float* __restrict__ feat, const float* __restrict__ edge,
    const float* __restrict__ wq, const float* __restrict__ bq,
    const float* __restrict__ wk, const float* __restrict__ bk,
    ushort_t* __restrict__ qT, ushort_t* __restrict__ kT)
{
    __shared__ float wqsT[CC][NI];       // transposed weights, 32 KB
    __shared__ float wksT[CC][NI];
    __shared__ float pq[4][64][36];      // per-wave partials, pad 36 for banks
    __shared__ float pk[4][64][36];

    const int tid = threadIdx.x;
    for (int r = 0; r < (NI * CC) / 256; ++r) {
        const int idx = r * 256 + tid;
        const int i = idx >> 8, c = idx & 255;
        wqsT[c][i] = wq[idx];
        wksT[c][i] = wk[idx];
    }
    __syncthreads();

    const int b = blockIdx.y;
    const int n0 = blockIdx.x * 64;
    const int w = tid >> 6, lane = tid & 63;

    float accq[NI], acck[NI];
#pragma unroll
    for (int i = 0; i < NI; ++i) { accq[i] = 0.f; acck[i] = 0.f; }

    const float* fp = feat + ((size_t)b * CC + w * 64) * NN + n0 + lane;
    const float* ep = edge + ((size_t)b * CC + w * 64) * NN + n0 + lane;
    for (int cc = 0; cc < 64; ++cc) {
        const int c = w * 64 + cc;
        const float f = fp[(size_t)cc * NN];
        const float e = ep[(size_t)cc * NN];
#pragma unroll
        for (int i4 = 0; i4 < NI / 4; ++i4) {
            const float4 a = *(const float4*)&wqsT[c][i4 * 4];
            const float4 g = *(const float4*)&wksT[c][i4 * 4];
            accq[i4 * 4 + 0] += a.x * f; accq[i4 * 4 + 1] += a.y * f;
            accq[i4 * 4 + 2] += a.z * f; accq[i4 * 4 + 3] += a.w * f;
            acck[i4 * 4 + 0] += g.x * e; acck[i4 * 4 + 1] += g.y * e;
            acck[i4 * 4 + 2] += g.z * e; acck[i4 * 4 + 3] += g.w * e;
        }
    }
#pragma unroll
    for (int i4 = 0; i4 < NI / 4; ++i4) {
        *(float4*)&pq[w][lane][i4 * 4] = make_float4(accq[i4*4], accq[i4*4+1], accq[i4*4+2], accq[i4*4+3]);
        *(float4*)&pk[w][lane][i4 * 4] = make_float4(acck[i4*4], acck[i4*4+1], acck[i4*4+2], acck[i4*4+3]);
    }
    __syncthreads();

    const int token = tid & 63, ig = tid >> 6;
    float sq[8], sk[8];
#pragma unroll
    for (int j = 0; j < 8; ++j) {
        const int i = ig * 8 + j;
        sq[j] = pq[0][token][i] + pq[1][token][i] + pq[2][token][i] + pq[3][token][i] + bq[i];
        sk[j] = pk[0][token][i] + pk[1][token][i] + pk[2][token][i] + pk[3][token][i] + bk[i];
    }
    uint4 uq, uk;
    uq.x = pack2bf(sq[0], sq[1]); uq.y = pack2bf(sq[2], sq[3]);
    uq.z = pack2bf(sq[4], sq[5]); uq.w = pack2bf(sq[6], sq[7]);
    uk.x = pack2bf(sk[0], sk[1]); uk.y = pack2bf(sk[2], sk[3]);
    uk.z = pack2bf(sk[4], sk[5]); uk.w = pack2bf(sk[6], sk[7]);
    const size_t ob = ((size_t)b * NN + n0 + token) * NI + ig * 8;
    *(uint4*)&qT[ob] = uq;
    *(uint4*)&kT[ob] = uk;
}

// ---------------------------------------------------------------- v projection (SGEMM, bf16 out)
__global__ __launch_bounds__(256) void v_kernel(
    const float* __restrict__ edge, const float* __restrict__ wv,
    const float* __restrict__ bv, ushort_t* __restrict__ v)
{
    __shared__ float es[64][68];
    __shared__ float wvs[64][65];
    const int tid = threadIdx.x;
    const int b  = blockIdx.z;
    const int o0 = blockIdx.y * 64;
    const int n0 = blockIdx.x * 64;
    const int ni = (tid & 15) * 4;
    const int oi = (tid >> 4) * 4;
    const int col  = tid & 63;
    const int row4 = tid >> 6;
    float acc[4][4];
#pragma unroll
    for (int i = 0; i < 4; ++i)
#pragma unroll
        for (int j = 0; j < 4; ++j) acc[i][j] = 0.f;

    for (int c0 = 0; c0 < CC; c0 += 64) {
#pragma unroll
        for (int r = 0; r < 16; ++r) {
            const int rr = row4 + 4 * r;
            es[rr][col]  = edge[(size_t)(b * CC + c0 + rr) * NN + n0 + col];
            wvs[rr][col] = wv[(size_t)(o0 + rr) * CC + c0 + col];
        }
        __syncthreads();
#pragma unroll 8
        for (int cc = 0; cc < 64; ++cc) {
            const float4 e4 = *(const float4*)&es[cc][ni];
            const float w0 = wvs[oi + 0][cc];
            const float w1 = wvs[oi + 1][cc];
            const float w2 = wvs[oi + 2][cc];
            const float w3 = wvs[oi + 3][cc];
            acc[0][0] += w0 * e4.x; acc[0][1] += w0 * e4.y; acc[0][2] += w0 * e4.z; acc[0][3] += w0 * e4.w;
            acc[1][0] += w1 * e4.x; acc[1][1] += w1 * e4.y; acc[1][2] += w1 * e4.z; acc[1][3] += w1 * e4.w;
            acc[2][0] += w2 * e4.x; acc[2][1] += w2 * e4.y; acc[2][2] += w2 * e4.z; acc[2][3] += w2 * e4.w;
            acc[3][0] += w3 * e4.x; acc[3][1] += w3 * e4.y; acc[3][2] += w3 * e4.z; acc[3][3] += w3 * e4.w;
        }
        __syncthreads();
    }
#pragma unroll
    for (int i = 0; i < 4; ++i) {
        const float bvv = bv[o0 + oi + i];
        ushort4 r;
        r.x = (ushort_t)f2bf_bits(acc[i][0] + bvv);
        r.y = (ushort_t)f2bf_bits(acc[i][1] + bvv);
        r.z = (ushort_t)f2bf_bits(acc[i][2] + bvv);
        r.w = (ushort_t)f2bf_bits(acc[i][3] + bvv);
        *(ushort4*)&v[(size_t)(b * CC + o0 + oi + i) * NN + n0 + ni] = r;
    }
}

// ---------------------------------------------------------------- barrier-free MFMA attention
// Grid (NN/64, B, 2): blockIdx.z picks a 128-channel half -> 512 blocks, 2/CU,
// 16 waves/CU. 512 thr / 8 waves; wave w: kg = w>>1 (1024 keys), chq = w&1
// (channels zch*128 + chq*64 .. +63). S computed per wave for both q-strips
// (cheap duplication); PV only for this block's channel half. Fixed-base
// softmax (|s| small by construction). Zero barriers in the k-loop.
// __launch_bounds__(512,4) caps unified VGPR at 128 so 2 blocks are resident.
__global__ __launch_bounds__(512, 4) void attn_kernel(
    const ushort_t* __restrict__ qT, const ushort_t* __restrict__ kT,
    const ushort_t* __restrict__ vT, const float* __restrict__ feat,
    float* __restrict__ out)
{
    __shared__ float red[4][64][33];     // [kg][q][c], 33.8 KB
    __shared__ float lpart[4][2][32];
    __shared__ float linvS[64];

    const int tid  = threadIdx.x;
    const int b    = blockIdx.y;
    const int zch  = blockIdx.z;
    const int nq0  = blockIdx.x * 64;
    const int w    = tid >> 6;
    const int lane = tid & 63;
    const int col  = lane & 31;
    const int h    = lane >> 5;
    const int chq  = w & 1;        // channel quarter within this block's half
    const int kg   = w >> 1;       // key group

    // Q B-frags for both q-strips (constant across the whole k-loop)
    bf16x8 bQ[2][2];
#pragma unroll
    for (int s = 0; s < 2; ++s) {
        const size_t qb = ((size_t)b * NN + nq0 + s * 32 + col) * NI + h * 8;
        bQ[s][0] = *(const bf16x8*)&qT[qb];
        bQ[s][1] = *(const bf16x8*)&qT[qb + 16];
    }

    f32x16 acc[2][2];   // [q-strip][local c-strip]
#pragma unroll
    for (int s = 0; s < 2; ++s)
#pragma unroll
        for (int cl = 0; cl < 2; ++cl)
#pragma unroll
            for (int r = 0; r < 16; ++r) acc[s][cl][r] = 0.f;

    float lp0 = 0.f, lp1 = 0.f;   // row-sum partials (query = col identity)

    const size_t kTb = (size_t)b * NN * NI;
    const size_t vB  = (size_t)b * CC * NN + (size_t)(zch * 128 + chq * 64 + col) * NN;
    const int keybase = kg * 1024;

    for (int strip = 0; strip < 32; ++strip) {
        const int key0 = keybase + strip * 32;

        // K A-frags: lane m = key, k = channel
        const size_t kb = kTb + (size_t)(key0 + col) * NI + h * 8;
        const bf16x8 aK0 = *(const bf16x8*)&kT[kb];
        const bf16x8 aK1 = *(const bf16x8*)&kT[kb + 16];

        fragU F[2][2];   // [q-strip][key chunk 0-15 / 16-31]
#pragma unroll
        for (int s = 0; s < 2; ++s) {
            f32x16 st;
#pragma unroll
            for (int r = 0; r < 16; ++r) st[r] = 0.f;
            st = __builtin_amdgcn_mfma_f32_32x32x16_bf16(aK0, bQ[s][0], st, 0, 0, 0);
            st = __builtin_amdgcn_mfma_f32_32x32x16_bf16(aK1, bQ[s][1], st, 0, 0, 0);

            // p = exp(s); per-lane row-sum partial (lane&31 = query)
            float p[16]; float sum = 0.f;
#pragma unroll
            for (int r = 0; r < 16; ++r) { p[r] = __expf(st[r]); sum += p[r]; }
            if (s == 0) lp0 += sum; else lp1 += sum;

            // pack key-consecutive pairs, exchange with lane^32, assemble A-frags.
            uint32 pk[8];
#pragma unroll
            for (int j = 0; j < 8; ++j) pk[j] = pack2bf(p[2 * j], p[2 * j + 1]);
            uint32 rv[8];
#pragma unroll
            for (int j = 0; j < 8; ++j) rv[j] = __shfl_xor(pk[j], 32, 64);
            F[s][0].u[0] = h ? rv[2] : pk[0];
            F[s][0].u[1] = h ? rv[3] : pk[1];
            F[s][0].u[2] = h ? pk[2] : rv[0];
            F[s][0].u[3] = h ? pk[3] : rv[1];
            F[s][1].u[0] = h ? rv[6] : pk[4];
            F[s][1].u[1] = h ? rv[7] : pk[5];
            F[s][1].u[2] = h ? pk[6] : rv[4];
            F[s][1].u[3] = h ? pk[7] : rv[5];
        }

        // V B-frags loaded after softmax (live-range split keeps VGPR <= 128)
#pragma unroll
        for (int cl = 0; cl < 2; ++cl) {
            const size_t vb = vB + (size_t)cl * 32 * NN + key0 + h * 8;
            const bf16x8 v0 = *(const bf16x8*)&vT[vb];
            const bf16x8 v1 = *(const bf16x8*)&vT[vb + 16];
            acc[0][cl] = __builtin_amdgcn_mfma_f32_32x32x16_bf16(F[0][0].v, v0, acc[0][cl], 0, 0, 0);
            acc[0][cl] = __builtin_amdgcn_mfma_f32_32x32x16_bf16(F[0][1].v, v1, acc[0][cl], 0, 0, 0);
            acc[1][cl] = __builtin_amdgcn_mfma_f32_32x32x16_bf16(F[1][0].v, v0, acc[1][cl], 0, 0, 0);
            acc[1][cl] = __builtin_amdgcn_mfma_f32_32x32x16_bf16(F[1][1].v, v1, acc[1][cl], 0, 0, 0);
        }
    }

    // ---- combine row sums: halves, then the 4 key groups (chq 0 only writes)
    lp0 += __shfl_xor(lp0, 32, 64);
    lp1 += __shfl_xor(lp1, 32, 64);
    if (chq == 0 && h == 0) { lpart[kg][0][col] = lp0; lpart[kg][1][col] = lp1; }
    __syncthreads();
    if (tid < 64) {
        const int s = tid >> 5, q = tid & 31;
        linvS[tid] = 1.0f / (lpart[0][s][q] + lpart[1][s][q] + lpart[2][s][q] + lpart[3][s][q]);
    }
    __syncthreads();

    const int c32 = tid >> 4;          // 0..31
    const int q4  = (tid & 15) * 4;    // 0..60
    float lv[4];
#pragma unroll
    for (int j = 0; j < 4; ++j) lv[j] = linvS[q4 + j];

    // ---- epilogue: 4 passes over (chq_p, cl_p); reduce over kg via LDS
    for (int pp = 0; pp < 4; ++pp) {
        const int chq_p = pp >> 1, cl_p = pp & 1;
        if (chq == chq_p) {
#pragma unroll
            for (int s = 0; s < 2; ++s)
#pragma unroll
                for (int r = 0; r < 16; ++r) {
                    const int row = s * 32 + (r & 3) + 8 * (r >> 2) + 4 * h;
                    red[kg][row][col] = acc[s][cl_p][r];
                }
        }
        __syncthreads();
        {
            const int cglob = zch * 128 + chq_p * 64 + cl_p * 32 + c32;
            const size_t gb = ((size_t)b * CC + cglob) * NN + nq0 + q4;
            float o[4];
#pragma unroll
            for (int j = 0; j < 4; ++j)
                o[j] = red[0][q4 + j][c32] + red[1][q4 + j][c32]
                     + red[2][q4 + j][c32] + red[3][q4 + j][c32];
            const float4 f4 = *(const float4*)&feat[gb];
            float4 o4;
            o4.x = o[0] * lv[0] + f4.x;
            o4.y = o[1] * lv[1] + f4.y;
            o4.z = o[2] * lv[2] + f4.z;
            o4.w = o[3] * lv[3] + f4.w;
            *(float4*)&out[gb] = o4;
        }
        __syncthreads();
    }
}

// ---------------------------------------------------------------- launch
extern "C" void kernel_launch(void* const* d_in, const int* in_sizes, int n_in,
                              void* d_out, int out_size, void* d_ws, size_t ws_size,
                              hipStream_t stream)
{
    (void)in_sizes; (void)n_in; (void)out_size; (void)ws_size;
    const float* feat = (const float*)d_in[0];
    const float* edge = (const float*)d_in[1];
    const float* wq   = (const float*)d_in[2];
    const float* bq   = (const float*)d_in[3];
    const float* wk   = (const float*)d_in[4];
    const float* bk   = (const float*)d_in[5];
    const float* wv   = (const float*)d_in[6];
    const float* bv   = (const float*)d_in[7];
    float* out = (float*)d_out;

    ushort_t* qT = (ushort_t*)d_ws;                       // [B][N][NI] bf16
    ushort_t* kT = qT + (size_t)BB * NN * NI;             // [B][N][NI] bf16
    ushort_t* vT = kT + (size_t)BB * NN * NI;             // [B][C][N]  bf16

    qk_kernel<<<dim3(NN / 64, BB), 256, 0, stream>>>(feat, edge, wq, bq, wk, bk, qT, kT);
    v_kernel<<<dim3(NN / 64, CC / 64, BB), 256, 0, stream>>>(edge, wv, bv, vT);
    attn_kernel<<<dim3(NN / 64, BB, 2), 512, 0, stream>>>(qT, kT, vT, feat, out);
}

// Round 6
// 207.083 us; speedup vs baseline: 2.2576x; 2.2576x over previous
//
#include <hip/hip_runtime.h>
#include <cstddef>

#define BB 4
#define CC 256
#define NN 4096
#define NI 32

typedef __attribute__((ext_vector_type(8))) short bf16x8;   // 8 bf16 = 4 VGPRs
typedef __attribute__((ext_vector_type(16))) float f32x16;  // MFMA 32x32 acc
typedef unsigned short ushort_t;
typedef unsigned int uint32;

typedef union { uint32 u[4]; bf16x8 v; } fragU;

__device__ __forceinline__ uint32 f2bf_bits(float f) {
    union { float f; uint32 u; } v; v.f = f;
    return (v.u + 0x7fffu + ((v.u >> 16) & 1u)) >> 16;   // RNE
}
__device__ __forceinline__ uint32 pack2bf(float a, float b) {
    return f2bf_bits(a) | (f2bf_bits(b) << 16);
}
// truncation pack (round-toward-zero): 2-3 VALU ops vs 8 for RNE. P-only.
__device__ __forceinline__ uint32 pack2bf_t(float a, float b) {
    union { float f; uint32 u; } A, B; A.f = a; B.f = b;
    return (B.u & 0xFFFF0000u) | (A.u >> 16);
}

// V fragment-order layout: vF[b][n/16][(n>>3)&1][c][n&7] (bf16)
// -> PV B-frag load is 16B/lane, lane-stride 16B (perfectly coalesced).
__device__ __forceinline__ size_t vfidx(int b, int n, int c) {
    return ((((size_t)b * (NN / 16) + (n >> 4)) * 2 + ((n >> 3) & 1)) * (CC * 8))
           + (size_t)c * 8 + (n & 7);
}

// ---------------------------------------------------------------- q,k projections
// Outputs token-major bf16: qT/kT [B][N][NI] — exactly MFMA frag order.
__global__ __launch_bounds__(256) void qk_kernel(
    const float* __restrict__ feat, const float* __restrict__ edge,
    const float* __restrict__ wq, const float* __restrict__ bq,
    const float* __restrict__ wk, const float* __restrict__ bk,
    ushort_t* __restrict__ qT, ushort_t* __restrict__ kT)
{
    __shared__ float wqsT[CC][NI];       // transposed weights, 32 KB
    __shared__ float wksT[CC][NI];
    __shared__ float pq[4][64][36];      // per-wave partials, pad 36 for banks
    __shared__ float pk[4][64][36];

    const int tid = threadIdx.x;
    for (int r = 0; r < (NI * CC) / 256; ++r) {
        const int idx = r * 256 + tid;
        const int i = idx >> 8, c = idx & 255;
        wqsT[c][i] = wq[idx];
        wksT[c][i] = wk[idx];
    }
    __syncthreads();

    const int b = blockIdx.y;
    const int n0 = blockIdx.x * 64;
    const int w = tid >> 6, lane = tid & 63;

    float accq[NI], acck[NI];
#pragma unroll
    for (int i = 0; i < NI; ++i) { accq[i] = 0.f; acck[i] = 0.f; }

    const float* fp = feat + ((size_t)b * CC + w * 64) * NN + n0 + lane;
    const float* ep = edge + ((size_t)b * CC + w * 64) * NN + n0 + lane;
    for (int cc = 0; cc < 64; ++cc) {
        const int c = w * 64 + cc;
        const float f = fp[(size_t)cc * NN];
        const float e = ep[(size_t)cc * NN];
#pragma unroll
        for (int i4 = 0; i4 < NI / 4; ++i4) {
            const float4 a = *(const float4*)&wqsT[c][i4 * 4];
            const float4 g = *(const float4*)&wksT[c][i4 * 4];
            accq[i4 * 4 + 0] += a.x * f; accq[i4 * 4 + 1] += a.y * f;
            accq[i4 * 4 + 2] += a.z * f; accq[i4 * 4 + 3] += a.w * f;
            acck[i4 * 4 + 0] += g.x * e; acck[i4 * 4 + 1] += g.y * e;
            acck[i4 * 4 + 2] += g.z * e; acck[i4 * 4 + 3] += g.w * e;
        }
    }
#pragma unroll
    for (int i4 = 0; i4 < NI / 4; ++i4) {
        *(float4*)&pq[w][lane][i4 * 4] = make_float4(accq[i4*4], accq[i4*4+1], accq[i4*4+2], accq[i4*4+3]);
        *(float4*)&pk[w][lane][i4 * 4] = make_float4(acck[i4*4], acck[i4*4+1], acck[i4*4+2], acck[i4*4+3]);
    }
    __syncthreads();

    const int token = tid & 63, ig = tid >> 6;
    float sq[8], sk[8];
#pragma unroll
    for (int j = 0; j < 8; ++j) {
        const int i = ig * 8 + j;
        sq[j] = pq[0][token][i] + pq[1][token][i] + pq[2][token][i] + pq[3][token][i] + bq[i];
        sk[j] = pk[0][token][i] + pk[1][token][i] + pk[2][token][i] + pk[3][token][i] + bk[i];
    }
    uint4 uq, uk;
    uq.x = pack2bf(sq[0], sq[1]); uq.y = pack2bf(sq[2], sq[3]);
    uq.z = pack2bf(sq[4], sq[5]); uq.w = pack2bf(sq[6], sq[7]);
    uk.x = pack2bf(sk[0], sk[1]); uk.y = pack2bf(sk[2], sk[3]);
    uk.z = pack2bf(sk[4], sk[5]); uk.w = pack2bf(sk[6], sk[7]);
    const size_t ob = ((size_t)b * NN + n0 + token) * NI + ig * 8;
    *(uint4*)&qT[ob] = uq;
    *(uint4*)&kT[ob] = uk;
}

// ---------------------------------------------------------------- v projection (SGEMM, frag-order bf16 out)
__global__ __launch_bounds__(256) void v_kernel(
    const float* __restrict__ edge, const float* __restrict__ wv,
    const float* __restrict__ bv, ushort_t* __restrict__ vF)
{
    __shared__ float es[64][68];
    __shared__ float wvs[64][65];
    const int tid = threadIdx.x;
    const int b  = blockIdx.z;
    const int o0 = blockIdx.y * 64;
    const int n0 = blockIdx.x * 64;
    const int ni = (tid & 15) * 4;
    const int oi = (tid >> 4) * 4;
    const int col  = tid & 63;
    const int row4 = tid >> 6;
    float acc[4][4];
#pragma unroll
    for (int i = 0; i < 4; ++i)
#pragma unroll
        for (int j = 0; j < 4; ++j) acc[i][j] = 0.f;

    for (int c0 = 0; c0 < CC; c0 += 64) {
#pragma unroll
        for (int r = 0; r < 16; ++r) {
            const int rr = row4 + 4 * r;
            es[rr][col]  = edge[(size_t)(b * CC + c0 + rr) * NN + n0 + col];
            wvs[rr][col] = wv[(size_t)(o0 + rr) * CC + c0 + col];
        }
        __syncthreads();
#pragma unroll 8
        for (int cc = 0; cc < 64; ++cc) {
            const float4 e4 = *(const float4*)&es[cc][ni];
            const float w0 = wvs[oi + 0][cc];
            const float w1 = wvs[oi + 1][cc];
            const float w2 = wvs[oi + 2][cc];
            const float w3 = wvs[oi + 3][cc];
            acc[0][0] += w0 * e4.x; acc[0][1] += w0 * e4.y; acc[0][2] += w0 * e4.z; acc[0][3] += w0 * e4.w;
            acc[1][0] += w1 * e4.x; acc[1][1] += w1 * e4.y; acc[1][2] += w1 * e4.z; acc[1][3] += w1 * e4.w;
            acc[2][0] += w2 * e4.x; acc[2][1] += w2 * e4.y; acc[2][2] += w2 * e4.z; acc[2][3] += w2 * e4.w;
            acc[3][0] += w3 * e4.x; acc[3][1] += w3 * e4.y; acc[3][2] += w3 * e4.z; acc[3][3] += w3 * e4.w;
        }
        __syncthreads();
    }
    // frag-order store: 4 consecutive keys (ni%8 in {0,4}) stay in one 8-block
#pragma unroll
    for (int i = 0; i < 4; ++i) {
        const float bvv = bv[o0 + oi + i];
        ushort4 r;
        r.x = (ushort_t)f2bf_bits(acc[i][0] + bvv);
        r.y = (ushort_t)f2bf_bits(acc[i][1] + bvv);
        r.z = (ushort_t)f2bf_bits(acc[i][2] + bvv);
        r.w = (ushort_t)f2bf_bits(acc[i][3] + bvv);
        *(ushort4*)&vF[vfidx(b, n0 + ni, o0 + oi + i)] = r;
    }
}

// ---------------------------------------------------------------- barrier-free MFMA attention
// 512 thr / 8 waves, grid (NN/64, B) = 256 blocks. Wave w: kg = w>>1 (1024
// keys), qs = w&1 (q-strip) -> S computed exactly ONCE chip-wide (no dup).
// Each wave does PV for ALL 256 channels (acc[8] = 128 regs). V loads are
// fully coalesced via the vF frag-order layout. Fixed-base softmax. Zero
// k-loop barriers. launch_bounds(512,2) = 256 unified regs (R5 lesson: less
// spills catastrophically).
__global__ __launch_bounds__(512, 2) void attn_kernel(
    const ushort_t* __restrict__ qT, const ushort_t* __restrict__ kT,
    const ushort_t* __restrict__ vF, const float* __restrict__ feat,
    float* __restrict__ out)
{
    __shared__ float red[4][64][33];     // [kg][q][c], 33.8 KB
    __shared__ float lpart[4][2][32];
    __shared__ float linvS[64];

    const int tid  = threadIdx.x;
    const int b    = blockIdx.y;
    const int nq0  = blockIdx.x * 64;
    const int w    = tid >> 6;
    const int lane = tid & 63;
    const int col  = lane & 31;
    const int h    = lane >> 5;
    const int qs   = w & 1;        // q-strip
    const int kg   = w >> 1;       // key group

    // Q B-frags for this wave's q-strip only (constant across the k-loop)
    bf16x8 bQ0, bQ1;
    {
        const size_t qb = ((size_t)b * NN + nq0 + qs * 32 + col) * NI + h * 8;
        bQ0 = *(const bf16x8*)&qT[qb];
        bQ1 = *(const bf16x8*)&qT[qb + 16];
    }

    f32x16 acc[8];   // one 32x32 tile per c-strip (128 regs)
#pragma unroll
    for (int cs = 0; cs < 8; ++cs)
#pragma unroll
        for (int r = 0; r < 16; ++r) acc[cs][r] = 0.f;

    float lp = 0.f;   // row-sum partial (lane col = query)

    const size_t kTb = (size_t)b * NN * NI;
    const int keybase = kg * 1024;

    for (int strip = 0; strip < 32; ++strip) {
        const int key0 = keybase + strip * 32;

        // K A-frags: lane m = key, k = channel
        const size_t kb = kTb + (size_t)(key0 + col) * NI + h * 8;
        const bf16x8 aK0 = *(const bf16x8*)&kT[kb];
        const bf16x8 aK1 = *(const bf16x8*)&kT[kb + 16];

        // S^T subtile for this q-strip: lane col = query, regs = keys
        f32x16 st;
#pragma unroll
        for (int r = 0; r < 16; ++r) st[r] = 0.f;
        st = __builtin_amdgcn_mfma_f32_32x32x16_bf16(aK0, bQ0, st, 0, 0, 0);
        st = __builtin_amdgcn_mfma_f32_32x32x16_bf16(aK1, bQ1, st, 0, 0, 0);

        // p = exp(s); row-sum in fp32; truncation-pack to bf16 pairs
        float p[16]; float sum = 0.f;
#pragma unroll
        for (int r = 0; r < 16; ++r) { p[r] = __expf(st[r]); sum += p[r]; }
        lp += sum;

        uint32 pk[8];
#pragma unroll
        for (int j = 0; j < 8; ++j) pk[j] = pack2bf_t(p[2 * j], p[2 * j + 1]);
        uint32 rv[8];
#pragma unroll
        for (int j = 0; j < 8; ++j) rv[j] = __shfl_xor(pk[j], 32, 64);
        fragU F0, F1;    // A-frags: key chunks 0-15 / 16-31
        F0.u[0] = h ? rv[2] : pk[0];
        F0.u[1] = h ? rv[3] : pk[1];
        F0.u[2] = h ? pk[2] : rv[0];
        F0.u[3] = h ? pk[3] : rv[1];
        F1.u[0] = h ? rv[6] : pk[4];
        F1.u[1] = h ? rv[7] : pk[5];
        F1.u[2] = h ? pk[6] : rv[4];
        F1.u[3] = h ? pk[7] : rv[5];

        // PV over all 8 c-strips; V loads coalesced (lane-stride 16B)
        const size_t vbB = (((size_t)b * (NN / 16) + (key0 >> 4)) * 2 + h) * (CC * 8)
                         + (size_t)col * 8;
#pragma unroll
        for (int cs = 0; cs < 8; ++cs) {
            const bf16x8 v0 = *(const bf16x8*)&vF[vbB + cs * 256];
            const bf16x8 v1 = *(const bf16x8*)&vF[vbB + 4096 + cs * 256];
            acc[cs] = __builtin_amdgcn_mfma_f32_32x32x16_bf16(F0.v, v0, acc[cs], 0, 0, 0);
            acc[cs] = __builtin_amdgcn_mfma_f32_32x32x16_bf16(F1.v, v1, acc[cs], 0, 0, 0);
        }
    }

    // ---- combine row sums: halves, then the 4 key groups
    lp += __shfl_xor(lp, 32, 64);
    if (h == 0) lpart[kg][qs][col] = lp;
    __syncthreads();
    if (tid < 64) {
        const int s = tid >> 5, q = tid & 31;
        linvS[tid] = 1.0f / (lpart[0][s][q] + lpart[1][s][q] + lpart[2][s][q] + lpart[3][s][q]);
    }
    __syncthreads();

    const int c32 = tid >> 4;          // 0..31
    const int q4  = (tid & 15) * 4;    // 0..60
    float lv[4];
#pragma unroll
    for (int j = 0; j < 4; ++j) lv[j] = linvS[q4 + j];

    // ---- epilogue: 8 passes (one per c-strip); reduce over kg via LDS
#pragma unroll
    for (int pp = 0; pp < 8; ++pp) {
#pragma unroll
        for (int r = 0; r < 16; ++r) {
            const int row = qs * 32 + (r & 3) + 8 * (r >> 2) + 4 * h;
            red[kg][row][col] = acc[pp][r];
        }
        __syncthreads();
        {
            const int cglob = pp * 32 + c32;
            const size_t gb = ((size_t)b * CC + cglob) * NN + nq0 + q4;
            float o[4];
#pragma unroll
            for (int j = 0; j < 4; ++j)
                o[j] = red[0][q4 + j][c32] + red[1][q4 + j][c32]
                     + red[2][q4 + j][c32] + red[3][q4 + j][c32];
            const float4 f4 = *(const float4*)&feat[gb];
            float4 o4;
            o4.x = o[0] * lv[0] + f4.x;
            o4.y = o[1] * lv[1] + f4.y;
            o4.z = o[2] * lv[2] + f4.z;
            o4.w = o[3] * lv[3] + f4.w;
            *(float4*)&out[gb] = o4;
        }
        __syncthreads();
    }
}

// ---------------------------------------------------------------- launch
extern "C" void kernel_launch(void* const* d_in, const int* in_sizes, int n_in,
                              void* d_out, int out_size, void* d_ws, size_t ws_size,
                              hipStream_t stream)
{
    (void)in_sizes; (void)n_in; (void)out_size; (void)ws_size;
    const float* feat = (const float*)d_in[0];
    const float* edge = (const float*)d_in[1];
    const float* wq   = (const float*)d_in[2];
    const float* bq   = (const float*)d_in[3];
    const float* wk   = (const float*)d_in[4];
    const float* bk   = (const float*)d_in[5];
    const float* wv   = (const float*)d_in[6];
    const float* bv   = (const float*)d_in[7];
    float* out = (float*)d_out;

    ushort_t* qT = (ushort_t*)d_ws;                       // [B][N][NI] bf16
    ushort_t* kT = qT + (size_t)BB * NN * NI;             // [B][N][NI] bf16
    ushort_t* vF = kT + (size_t)BB * NN * NI;             // frag-order V, bf16

    qk_kernel<<<dim3(NN / 64, BB), 256, 0, stream>>>(feat, edge, wq, bq, wk, bk, qT, kT);
    v_kernel<<<dim3(NN / 64, CC / 64, BB), 256, 0, stream>>>(edge, wv, bv, vF);
    attn_kernel<<<dim3(NN / 64, BB), 512, 0, stream>>>(qT, kT, vF, feat, out);
}